// Round 5
// baseline (281.907 us; speedup 1.0000x reference)
//
#include <hip/hip_runtime.h>
#include <math.h>

#define N_NODES_C 50000
#define N_EDGES_C 800000
#define D_FEAT_C  64
#define ROWSTR 72                         // floats per staged row (64 + 8 pad)
#define WAVE_LDS_FLOATS (16 * ROWSTR + 64)  // 16 rows + nhd vector

// ---------------- CSR build ----------------

__global__ void deg_kernel(const int* __restrict__ dst, int* __restrict__ deg, int nE) {
    int i = blockIdx.x * blockDim.x + threadIdx.x;
    if (i < nE) atomicAdd(&deg[dst[i]], 1);
}

// Single-block exclusive scan, 4 elements/thread (int4). n must be mult of 4 (50000 is).
__global__ void exscan_kernel(const int* __restrict__ deg, int* __restrict__ offs,
                              int* __restrict__ cursor, int n) {
    __shared__ int lds[16];
    __shared__ int carry_s;
    const int tid  = threadIdx.x;          // blockDim.x == 1024
    const int lane = tid & 63;
    const int wid  = tid >> 6;             // 16 waves
    if (tid == 0) carry_s = 0;
    __syncthreads();
    for (int base = 0; base < n; base += 4096) {
        int i = base + tid * 4;
        int4 v = make_int4(0, 0, 0, 0);
        if (i < n) v = *(const int4*)(deg + i);   // n%4==0 -> safe
        int tsum = v.x + v.y + v.z + v.w;
        int x = tsum;
        #pragma unroll
        for (int off = 1; off < 64; off <<= 1) {
            int y = __shfl_up(x, off, 64);
            if (lane >= off) x += y;
        }
        if (lane == 63) lds[wid] = x;
        __syncthreads();
        if (tid < 16) {
            int w = lds[tid];
            #pragma unroll
            for (int off = 1; off < 16; off <<= 1) {
                int y = __shfl_up(w, off, 16);
                if (tid >= off) w += y;
            }
            lds[tid] = w;
        }
        __syncthreads();
        int waveoff = wid ? lds[wid - 1] : 0;
        int excl = carry_s + waveoff + (x - tsum);
        if (i < n) {
            int4 o;
            o.x = excl;
            o.y = o.x + v.x;
            o.z = o.y + v.y;
            o.w = o.z + v.z;
            *(int4*)(offs + i)   = o;
            *(int4*)(cursor + i) = o;
        }
        __syncthreads();
        if (tid == 1023) carry_s += lds[15];
        __syncthreads();
    }
    if (tid == 0) offs[n] = carry_s;
}

__global__ void fill_kernel(const int* __restrict__ src, const int* __restrict__ dst,
                            int* __restrict__ cursor, int* __restrict__ csr_src, int nE) {
    int i = blockIdx.x * blockDim.x + threadIdx.x;
    if (i < nE) {
        int pos = atomicAdd(&cursor[dst[i]], 1);
        csr_src[pos] = src[i];
    }
}

// ---------------- per-layer kernels ----------------

__global__ void invnorm_kernel(const float* __restrict__ h, float* __restrict__ invn, int n) {
    int wave = (blockIdx.x * blockDim.x + threadIdx.x) >> 6;
    int lane = threadIdx.x & 63;
    if (wave >= n) return;
    float x = h[wave * D_FEAT_C + lane];
    float ss = x * x;
    #pragma unroll
    for (int off = 32; off; off >>= 1) ss += __shfl_xor(ss, off, 64);
    if (lane == 0) invn[wave] = 1.0f / fmaxf(sqrtf(ss), 1e-12f);
}

// Wave per dst node; edges processed in chunks of 16.
// Stage 16 src rows (reg + LDS mirror), transposed-lane dot (lane = 4*edge+quarter,
// 16 fma + 2 shuffles per 16 edges), one online-softmax merge per chunk,
// aggregation from registers via readlane weights. Exact same online-softmax math
// as the proven R4 kernel, amortized 16x.
__global__ void __launch_bounds__(256)
agnn_node_kernel(const float* __restrict__ h, const float* __restrict__ invn,
                 const int* __restrict__ offs, const int* __restrict__ csr_src,
                 const float* __restrict__ beta_ptr, int layer,
                 float* __restrict__ out, float* __restrict__ invn_out, int n) {
    __shared__ __align__(16) float smem[4 * WAVE_LDS_FLOATS];
    const int tid  = threadIdx.x;
    const int lane = tid & 63;
    const int wid  = tid >> 6;
    float* rowbuf = smem + wid * WAVE_LDS_FLOATS;   // [16][ROWSTR]
    float* nhbuf  = rowbuf + 16 * ROWSTR;           // [64]

    int node = blockIdx.x * 4 + wid;
    if (node >= n) return;
    int s = offs[node], e = offs[node + 1];

    const int eq = lane >> 2;   // edge slot 0..15
    const int q  = lane & 3;    // feature quarter 0..3

    float res = 0.f;
    if (e > s) {                                  // wave-uniform
        float beta = beta_ptr[layer];
        float invd = invn[node];
        nhbuf[lane] = h[node * D_FEAT_C + lane] * invd;
        float m = -INFINITY, den = 0.f, acc = 0.f;
        for (int base = s; base < e; base += 64) {
            int idx  = base + lane;
            int eidx = (idx < e) ? csr_src[idx] : 0;   // coalesced batch of edge ids
            int nb   = min(64, e - base);               // wave-uniform
            for (int c = 0; c < 4 && c * 16 < nb; ++c) {
                int nbc = min(16, nb - c * 16);          // valid edges in chunk (uniform)
                // ---- stage rows: global -> reg (+ LDS mirror) ----
                float r[16];
                #pragma unroll
                for (int t = 0; t < 16; ++t) {
                    if (t < nbc) {                       // uniform branch
                        int u = __builtin_amdgcn_readlane(eidx, c * 16 + t);
                        r[t] = h[u * D_FEAT_C + lane];   // coalesced 256B row
                        rowbuf[t * ROWSTR + lane] = r[t];
                    } else {
                        r[t] = 0.f;
                    }
                }
                // per-lane src id for this lane's edge slot -> invn gather
                int u_eq = __shfl(eidx, c * 16 + eq, 64);
                float iu = invn[u_eq];
                // ---- dot phase: transposed LDS read ----
                const float4* rp = (const float4*)(rowbuf + eq * ROWSTR + q * 16);
                const float4* np = (const float4*)(nhbuf + q * 16);
                float d0 = 0.f, d1 = 0.f;
                #pragma unroll
                for (int k = 0; k < 4; k += 2) {
                    float4 rv0 = rp[k],     nv0 = np[k];
                    float4 rv1 = rp[k + 1], nv1 = np[k + 1];
                    d0 += rv0.x * nv0.x + rv0.y * nv0.y + rv0.z * nv0.z + rv0.w * nv0.w;
                    d1 += rv1.x * nv1.x + rv1.y * nv1.y + rv1.z * nv1.z + rv1.w * nv1.w;
                }
                float dsum = d0 + d1;
                dsum += __shfl_xor(dsum, 1, 64);
                dsum += __shfl_xor(dsum, 2, 64);         // all 4 lanes of quad: full dot
                float sc_e = (beta * iu) * dsum;          // edge score
                if (eq >= nbc) sc_e = -INFINITY;          // mask invalid slots (NaN-safe)
                // ---- chunk max over 16 slots ----
                float cm = sc_e;
                cm = fmaxf(cm, __shfl_xor(cm, 4, 64));
                cm = fmaxf(cm, __shfl_xor(cm, 8, 64));
                cm = fmaxf(cm, __shfl_xor(cm, 16, 64));
                cm = fmaxf(cm, __shfl_xor(cm, 32, 64));
                float M = fmaxf(m, cm);
                float w = __expf(sc_e - M);               // 0 for invalid slots
                float ws = w;
                ws += __shfl_xor(ws, 4, 64);
                ws += __shfl_xor(ws, 8, 64);
                ws += __shfl_xor(ws, 16, 64);
                ws += __shfl_xor(ws, 32, 64);             // den of this chunk
                float scale = __expf(m - M);              // 0 on first chunk
                den = den * scale + ws;
                acc = acc * scale;
                // ---- aggregation from registers ----
                #pragma unroll
                for (int t = 0; t < 16; ++t) {
                    float wt = __int_as_float(
                        __builtin_amdgcn_readlane(__float_as_int(w), 4 * t));
                    acc += wt * r[t];                     // invalid: wt=0 and r[t]=0
                }
                m = M;
            }
        }
        res = acc / den;                                  // = sum h[src]*p
    }
    float ro = fmaxf(res, 0.f);                           // relu; deg-0 -> 0
    out[node * D_FEAT_C + lane] = ro;
    if (invn_out) {
        float ss = ro * ro;
        #pragma unroll
        for (int off = 32; off; off >>= 1) ss += __shfl_xor(ss, off, 64);
        if (lane == 0) invn_out[node] = 1.0f / fmaxf(sqrtf(ss), 1e-12f);
    }
}

// ---------------- launch ----------------

extern "C" void kernel_launch(void* const* d_in, const int* in_sizes, int n_in,
                              void* d_out, int out_size, void* d_ws, size_t ws_size,
                              hipStream_t stream) {
    const float* x    = (const float*)d_in[0];
    const int*   src  = (const int*)d_in[1];
    const int*   dst  = (const int*)d_in[2];
    const float* beta = (const float*)d_in[3];
    float*       out  = (float*)d_out;

    const int N = N_NODES_C, E = N_EDGES_C;

    char* p = (char*)d_ws;
    auto take = [&](size_t bytes) { char* r = p; p += (bytes + 255) & ~size_t(255); return r; };
    int*   deg     = (int*)  take(sizeof(int) * N);
    int*   offs    = (int*)  take(sizeof(int) * (N + 1));
    int*   cursor  = (int*)  take(sizeof(int) * N);
    int*   csr_src = (int*)  take(sizeof(int) * E);
    float* invnA   = (float*)take(sizeof(float) * N);
    float* invnB   = (float*)take(sizeof(float) * N);
    float* h1      = (float*)take(sizeof(float) * N * D_FEAT_C);

    // CSR by dst (layer-invariant)
    hipMemsetAsync(deg, 0, sizeof(int) * N, stream);
    deg_kernel<<<(E + 255) / 256, 256, 0, stream>>>(dst, deg, E);
    exscan_kernel<<<1, 1024, 0, stream>>>(deg, offs, cursor, N);
    fill_kernel<<<(E + 255) / 256, 256, 0, stream>>>(src, dst, cursor, csr_src, E);

    const int node_blocks = (N + 3) / 4;   // 4 waves (nodes) per 256-thread block

    // layer 0: x -> h1  (also emits invnB for layer 1)
    invnorm_kernel<<<node_blocks, 256, 0, stream>>>(x, invnA, N);
    agnn_node_kernel<<<node_blocks, 256, 0, stream>>>(x, invnA, offs, csr_src, beta, 0, h1, invnB, N);

    // layer 1: h1 -> out
    agnn_node_kernel<<<node_blocks, 256, 0, stream>>>(h1, invnB, offs, csr_src, beta, 1, out, nullptr, N);
}

// Round 6
// 279.696 us; speedup vs baseline: 1.0079x; 1.0079x over previous
//
#include <hip/hip_runtime.h>
#include <hip/hip_fp16.h>
#include <math.h>

#define N_NODES_C 50000
#define N_EDGES_C 800000
#define D_FEAT_C  64

// ---------------- CSR build ----------------

__global__ void deg_kernel(const int* __restrict__ dst, int* __restrict__ deg, int nE) {
    int i = blockIdx.x * blockDim.x + threadIdx.x;
    if (i < nE) atomicAdd(&deg[dst[i]], 1);
}

// Single-block exclusive scan, 4 elements/thread (int4). n must be mult of 4 (50000 is).
__global__ void exscan_kernel(const int* __restrict__ deg, int* __restrict__ offs,
                              int* __restrict__ cursor, int n) {
    __shared__ int lds[16];
    __shared__ int carry_s;
    const int tid  = threadIdx.x;          // blockDim.x == 1024
    const int lane = tid & 63;
    const int wid  = tid >> 6;             // 16 waves
    if (tid == 0) carry_s = 0;
    __syncthreads();
    for (int base = 0; base < n; base += 4096) {
        int i = base + tid * 4;
        int4 v = make_int4(0, 0, 0, 0);
        if (i < n) v = *(const int4*)(deg + i);   // n%4==0 -> safe
        int tsum = v.x + v.y + v.z + v.w;
        int x = tsum;
        #pragma unroll
        for (int off = 1; off < 64; off <<= 1) {
            int y = __shfl_up(x, off, 64);
            if (lane >= off) x += y;
        }
        if (lane == 63) lds[wid] = x;
        __syncthreads();
        if (tid < 16) {
            int w = lds[tid];
            #pragma unroll
            for (int off = 1; off < 16; off <<= 1) {
                int y = __shfl_up(w, off, 16);
                if (tid >= off) w += y;
            }
            lds[tid] = w;
        }
        __syncthreads();
        int waveoff = wid ? lds[wid - 1] : 0;
        int excl = carry_s + waveoff + (x - tsum);
        if (i < n) {
            int4 o;
            o.x = excl;
            o.y = o.x + v.x;
            o.z = o.y + v.y;
            o.w = o.z + v.z;
            *(int4*)(offs + i)   = o;
            *(int4*)(cursor + i) = o;
        }
        __syncthreads();
        if (tid == 1023) carry_s += lds[15];
        __syncthreads();
    }
    if (tid == 0) offs[n] = carry_s;
}

__global__ void fill_kernel(const int* __restrict__ src, const int* __restrict__ dst,
                            int* __restrict__ cursor, int* __restrict__ csr_src, int nE) {
    int i = blockIdx.x * blockDim.x + threadIdx.x;
    if (i < nE) {
        int pos = atomicAdd(&cursor[dst[i]], 1);
        csr_src[pos] = src[i];
    }
}

// ---------------- per-layer kernels ----------------

// Wave per node: 1/max(||row||,eps) from fp32 x, plus fused fp32->fp16 row copy.
__global__ void invnorm_cvt_kernel(const float* __restrict__ h, float* __restrict__ invn,
                                   __half* __restrict__ hh, int n) {
    int wave = (blockIdx.x * blockDim.x + threadIdx.x) >> 6;
    int lane = threadIdx.x & 63;
    if (wave >= n) return;
    float x = h[wave * D_FEAT_C + lane];
    hh[wave * D_FEAT_C + lane] = __float2half(x);
    float ss = x * x;
    #pragma unroll
    for (int off = 32; off; off >>= 1) ss += __shfl_xor(ss, off, 64);
    if (lane == 0) invn[wave] = 1.0f / fmaxf(sqrtf(ss), 1e-12f);
}

// Wave per dst node. R4-proven no-LDS structure, widened to 8-edge ILP groups.
// Rows gathered as fp16 (128B = one cache line per row), all math fp32.
// One online-softmax merge per 8-edge group; tail slots masked to -inf (exact).
// Writes fp32 out and/or fp16 out; optionally emits invnorm of the relu'd row.
__global__ void __launch_bounds__(256)
agnn_node_kernel(const __half* __restrict__ hh, const float* __restrict__ invn,
                 const int* __restrict__ offs, const int* __restrict__ csr_src,
                 const float* __restrict__ beta_ptr, int layer,
                 float* __restrict__ outF, __half* __restrict__ outH,
                 float* __restrict__ invn_out, int n) {
    int wave = (blockIdx.x * blockDim.x + threadIdx.x) >> 6;
    int lane = threadIdx.x & 63;
    if (wave >= n) return;
    int s = offs[wave], e = offs[wave + 1];
    float res = 0.f;
    if (e > s) {                              // wave-uniform
        float beta = beta_ptr[layer];
        float nhd  = __half2float(hh[wave * D_FEAT_C + lane]) * invn[wave];
        float m = -INFINITY, den = 0.f, acc = 0.f;
        for (int base = s; base < e; base += 64) {
            int idx  = base + lane;
            int eidx = (idx < e) ? csr_src[idx] : 0;   // coalesced batch of 64 edge ids
            int nb   = min(64, e - base);               // wave-uniform
            for (int jj = 0; jj < nb; jj += 8) {
                float hu[8], sc[8];
                #pragma unroll
                for (int t = 0; t < 8; ++t) {
                    int jc = (jj + t < nb) ? jj + t : jj;   // uniform clamp
                    int u  = __shfl(eidx, jc, 64);           // uniform -> readlane
                    sc[t]  = invn[u];                        // scalar load
                    hu[t]  = __half2float(hh[u * D_FEAT_C + lane]);  // 128B row gather
                }
                float d[8];
                #pragma unroll
                for (int t = 0; t < 8; ++t) d[t] = nhd * hu[t];
                #pragma unroll
                for (int off = 32; off; off >>= 1) {   // 8 interleaved reduce trees
                    #pragma unroll
                    for (int t = 0; t < 8; ++t) d[t] += __shfl_xor(d[t], off, 64);
                }
                #pragma unroll
                for (int t = 0; t < 8; ++t)
                    sc[t] = (jj + t < nb) ? beta * d[t] * sc[t] : -INFINITY;
                float a0 = fmaxf(sc[0], sc[1]), a1 = fmaxf(sc[2], sc[3]);
                float a2 = fmaxf(sc[4], sc[5]), a3 = fmaxf(sc[6], sc[7]);
                float M8 = fmaxf(fmaxf(a0, a1), fmaxf(a2, a3));
                float w[8];
                #pragma unroll
                for (int t = 0; t < 8; ++t) w[t] = __expf(sc[t] - M8);  // invalid -> 0
                float den8 = ((w[0] + w[1]) + (w[2] + w[3])) + ((w[4] + w[5]) + (w[6] + w[7]));
                float acc8 = 0.f;
                #pragma unroll
                for (int t = 0; t < 8; ++t) acc8 += w[t] * hu[t];
                // single online merge per group
                float mn = fmaxf(m, M8);
                float s0 = __expf(m - mn);     // 0 on first group (m=-inf)
                float s1 = __expf(M8 - mn);
                den = den * s0 + den8 * s1;
                acc = acc * s0 + acc8 * s1;
                m = mn;
            }
        }
        res = acc / den;                      // = sum h[src]*p
    }
    float ro = fmaxf(res, 0.f);               // relu; deg-0 nodes -> 0
    if (outF) outF[wave * D_FEAT_C + lane] = ro;
    if (outH) outH[wave * D_FEAT_C + lane] = __float2half(ro);
    if (invn_out) {
        float ss = ro * ro;
        #pragma unroll
        for (int off = 32; off; off >>= 1) ss += __shfl_xor(ss, off, 64);
        if (lane == 0) invn_out[wave] = 1.0f / fmaxf(sqrtf(ss), 1e-12f);
    }
}

// ---------------- launch ----------------

extern "C" void kernel_launch(void* const* d_in, const int* in_sizes, int n_in,
                              void* d_out, int out_size, void* d_ws, size_t ws_size,
                              hipStream_t stream) {
    const float* x    = (const float*)d_in[0];
    const int*   src  = (const int*)d_in[1];
    const int*   dst  = (const int*)d_in[2];
    const float* beta = (const float*)d_in[3];
    float*       out  = (float*)d_out;

    const int N = N_NODES_C, E = N_EDGES_C;

    char* p = (char*)d_ws;
    auto take = [&](size_t bytes) { char* r = p; p += (bytes + 255) & ~size_t(255); return r; };
    int*    deg     = (int*)   take(sizeof(int) * N);
    int*    offs    = (int*)   take(sizeof(int) * (N + 1));
    int*    cursor  = (int*)   take(sizeof(int) * N);
    int*    csr_src = (int*)   take(sizeof(int) * E);
    float*  invnA   = (float*) take(sizeof(float) * N);
    float*  invnB   = (float*) take(sizeof(float) * N);
    __half* xh      = (__half*)take(sizeof(__half) * N * D_FEAT_C);
    __half* h1h     = (__half*)take(sizeof(__half) * N * D_FEAT_C);

    // CSR by dst (layer-invariant)
    hipMemsetAsync(deg, 0, sizeof(int) * N, stream);
    deg_kernel<<<(E + 255) / 256, 256, 0, stream>>>(dst, deg, E);
    exscan_kernel<<<1, 1024, 0, stream>>>(deg, offs, cursor, N);
    fill_kernel<<<(E + 255) / 256, 256, 0, stream>>>(src, dst, cursor, csr_src, E);

    const int node_blocks = (N + 3) / 4;   // 4 waves (nodes) per 256-thread block

    // layer 0: x -> h1h (half) + invnB; invn/hh from fused invnorm+cvt
    invnorm_cvt_kernel<<<node_blocks, 256, 0, stream>>>(x, invnA, xh, N);
    agnn_node_kernel<<<node_blocks, 256, 0, stream>>>(xh, invnA, offs, csr_src, beta, 0,
                                                      nullptr, h1h, invnB, N);

    // layer 1: h1h -> out (fp32)
    agnn_node_kernel<<<node_blocks, 256, 0, stream>>>(h1h, invnB, offs, csr_src, beta, 1,
                                                      out, nullptr, nullptr, N);
}

// Round 7
// 191.149 us; speedup vs baseline: 1.4748x; 1.4632x over previous
//
#include <hip/hip_runtime.h>
#include <hip/hip_fp16.h>
#include <math.h>

#define N_NODES_C 50000
#define N_EDGES_C 800000
#define D_FEAT_C  64

// ---------------- CSR build ----------------

__global__ void deg_kernel(const int* __restrict__ dst, int* __restrict__ deg, int nE) {
    int i = blockIdx.x * blockDim.x + threadIdx.x;
    if (i < nE) atomicAdd(&deg[dst[i]], 1);
}

// Single-block exclusive scan, 4 elements/thread (int4). n must be mult of 4 (50000 is).
__global__ void exscan_kernel(const int* __restrict__ deg, int* __restrict__ offs,
                              int* __restrict__ cursor, int n) {
    __shared__ int lds[16];
    __shared__ int carry_s;
    const int tid  = threadIdx.x;          // blockDim.x == 1024
    const int lane = tid & 63;
    const int wid  = tid >> 6;             // 16 waves
    if (tid == 0) carry_s = 0;
    __syncthreads();
    for (int base = 0; base < n; base += 4096) {
        int i = base + tid * 4;
        int4 v = make_int4(0, 0, 0, 0);
        if (i < n) v = *(const int4*)(deg + i);   // n%4==0 -> safe
        int tsum = v.x + v.y + v.z + v.w;
        int x = tsum;
        #pragma unroll
        for (int off = 1; off < 64; off <<= 1) {
            int y = __shfl_up(x, off, 64);
            if (lane >= off) x += y;
        }
        if (lane == 63) lds[wid] = x;
        __syncthreads();
        if (tid < 16) {
            int w = lds[tid];
            #pragma unroll
            for (int off = 1; off < 16; off <<= 1) {
                int y = __shfl_up(w, off, 16);
                if (tid >= off) w += y;
            }
            lds[tid] = w;
        }
        __syncthreads();
        int waveoff = wid ? lds[wid - 1] : 0;
        int excl = carry_s + waveoff + (x - tsum);
        if (i < n) {
            int4 o;
            o.x = excl;
            o.y = o.x + v.x;
            o.z = o.y + v.y;
            o.w = o.z + v.z;
            *(int4*)(offs + i)   = o;
            *(int4*)(cursor + i) = o;
        }
        __syncthreads();
        if (tid == 1023) carry_s += lds[15];
        __syncthreads();
    }
    if (tid == 0) offs[n] = carry_s;
}

__global__ void fill_kernel(const int* __restrict__ src, const int* __restrict__ dst,
                            int* __restrict__ cursor, int* __restrict__ csr_src, int nE) {
    int i = blockIdx.x * blockDim.x + threadIdx.x;
    if (i < nE) {
        int pos = atomicAdd(&cursor[dst[i]], 1);
        csr_src[pos] = src[i];
    }
}

// ---------------- per-layer kernels ----------------

// Wave per node: 1/max(||row||,eps) from fp32 x, plus fused fp32->fp16 row copy.
__global__ void invnorm_cvt_kernel(const float* __restrict__ h, float* __restrict__ invn,
                                   __half* __restrict__ hh, int n) {
    int wave = (blockIdx.x * blockDim.x + threadIdx.x) >> 6;
    int lane = threadIdx.x & 63;
    if (wave >= n) return;
    float x = h[wave * D_FEAT_C + lane];
    hh[wave * D_FEAT_C + lane] = __float2half(x);
    float ss = x * x;
    #pragma unroll
    for (int off = 32; off; off >>= 1) ss += __shfl_xor(ss, off, 64);
    if (lane == 0) invn[wave] = 1.0f / fmaxf(sqrtf(ss), 1e-12f);
}

// Wave per dst node; quarter-wave (16 lanes x 4 features) per edge, 4 edges/chunk.
// One 8B load per lane fetches 4 complete fp16 rows per wave-instruction.
// Dot reduce: 4 levels within quarter. Wave-uniform running max (cross-quarter
// fmax each chunk) => uniform rescale => per-quarter den/acc partials are exact;
// summed across quarters once at the end. Raw-row dots with invn folded into
// the score (exact zeros for degenerate rows).
__global__ void __launch_bounds__(256)
agnn_node_kernel(const __half* __restrict__ hh, const float* __restrict__ invn,
                 const int* __restrict__ offs, const int* __restrict__ csr_src,
                 const float* __restrict__ beta_ptr, int layer,
                 float* __restrict__ outF, __half* __restrict__ outH,
                 float* __restrict__ invn_out, int n) {
    int wave = (blockIdx.x * blockDim.x + threadIdx.x) >> 6;
    int lane = threadIdx.x & 63;
    if (wave >= n) return;
    int s = offs[wave], e = offs[wave + 1];
    const int q16 = lane >> 4;   // quarter (edge slot in chunk)
    const int fl  = lane & 15;   // feature group: features 4*fl .. 4*fl+3
    float4 ro = make_float4(0.f, 0.f, 0.f, 0.f);
    if (e > s) {                              // wave-uniform
        float invd = invn[wave];
        float bi   = beta_ptr[layer] * invd;
        // dst raw row slice (features 4*fl..+3)
        uint2 ndl = *(const uint2*)(hh + wave * D_FEAT_C + 4 * fl);
        float2 n0 = __half22float2(*(__half2*)&ndl.x);
        float2 n1 = __half22float2(*(__half2*)&ndl.y);
        float m = -INFINITY, den = 0.f;
        float4 acc = make_float4(0.f, 0.f, 0.f, 0.f);
        for (int base = s; base < e; base += 64) {
            int idx  = base + lane;
            int eidx = (idx < e) ? csr_src[idx] : 0;   // coalesced batch of 64 edge ids
            int nb   = min(64, e - base);               // wave-uniform
            for (int jj = 0; jj < nb; jj += 4) {
                int  t     = jj + q16;
                bool valid = t < nb;                    // uniform within quarter
                int  tc    = valid ? t : jj;
                int  u     = __shfl(eidx, tc, 64);      // per-quarter src id
                float iu   = invn[u];
                uint2 hul  = *(const uint2*)(hh + u * D_FEAT_C + 4 * fl);  // 8B -> 512B/wave
                float2 f0  = __half22float2(*(__half2*)&hul.x);
                float2 f1  = __half22float2(*(__half2*)&hul.y);
                float d = f0.x * n0.x + f0.y * n0.y + f1.x * n1.x + f1.y * n1.y;
                d += __shfl_xor(d, 1, 64);
                d += __shfl_xor(d, 2, 64);
                d += __shfl_xor(d, 4, 64);
                d += __shfl_xor(d, 8, 64);              // full dot, uniform in quarter
                float sc = valid ? bi * d * iu : -INFINITY;
                float M4 = fmaxf(sc, __shfl_xor(sc, 16, 64));
                M4 = fmaxf(M4, __shfl_xor(M4, 32, 64)); // chunk max, wave-uniform
                float M  = fmaxf(m, M4);
                float w  = __expf(sc - M);              // 0 for invalid slots
                float scale = __expf(m - M);            // 0 on first chunk
                den   = den   * scale + w;              // own-quarter partial
                acc.x = acc.x * scale + w * f0.x;
                acc.y = acc.y * scale + w * f0.y;
                acc.z = acc.z * scale + w * f1.x;
                acc.w = acc.w * scale + w * f1.y;
                m = M;
            }
        }
        // cross-quarter reduction (same m everywhere -> exact)
        den += __shfl_xor(den, 16, 64);  den += __shfl_xor(den, 32, 64);
        acc.x += __shfl_xor(acc.x, 16, 64);  acc.x += __shfl_xor(acc.x, 32, 64);
        acc.y += __shfl_xor(acc.y, 16, 64);  acc.y += __shfl_xor(acc.y, 32, 64);
        acc.z += __shfl_xor(acc.z, 16, 64);  acc.z += __shfl_xor(acc.z, 32, 64);
        acc.w += __shfl_xor(acc.w, 16, 64);  acc.w += __shfl_xor(acc.w, 32, 64);
        float inv_den = 1.0f / den;
        ro.x = fmaxf(acc.x * inv_den, 0.f);
        ro.y = fmaxf(acc.y * inv_den, 0.f);
        ro.z = fmaxf(acc.z * inv_den, 0.f);
        ro.w = fmaxf(acc.w * inv_den, 0.f);
    }
    // all quarters hold identical ro (features 4*fl..+3); quarter 0 writes
    if (outF && lane < 16) ((float4*)(outF + wave * D_FEAT_C))[fl] = ro;
    if (outH && lane < 16) {
        __half2 a = __floats2half2_rn(ro.x, ro.y);
        __half2 b = __floats2half2_rn(ro.z, ro.w);
        uint2 pk;
        pk.x = *(unsigned*)&a;
        pk.y = *(unsigned*)&b;
        *(uint2*)(outH + wave * D_FEAT_C + 4 * fl) = pk;
    }
    if (invn_out) {
        float ss = ro.x * ro.x + ro.y * ro.y + ro.z * ro.z + ro.w * ro.w;
        ss += __shfl_xor(ss, 1, 64);
        ss += __shfl_xor(ss, 2, 64);
        ss += __shfl_xor(ss, 4, 64);
        ss += __shfl_xor(ss, 8, 64);        // sum within quarter = full ||row||^2
        if (lane == 0) invn_out[wave] = 1.0f / fmaxf(sqrtf(ss), 1e-12f);
    }
}

// ---------------- launch ----------------

extern "C" void kernel_launch(void* const* d_in, const int* in_sizes, int n_in,
                              void* d_out, int out_size, void* d_ws, size_t ws_size,
                              hipStream_t stream) {
    const float* x    = (const float*)d_in[0];
    const int*   src  = (const int*)d_in[1];
    const int*   dst  = (const int*)d_in[2];
    const float* beta = (const float*)d_in[3];
    float*       out  = (float*)d_out;

    const int N = N_NODES_C, E = N_EDGES_C;

    char* p = (char*)d_ws;
    auto take = [&](size_t bytes) { char* r = p; p += (bytes + 255) & ~size_t(255); return r; };
    int*    deg     = (int*)   take(sizeof(int) * N);
    int*    offs    = (int*)   take(sizeof(int) * (N + 1));
    int*    cursor  = (int*)   take(sizeof(int) * N);
    int*    csr_src = (int*)   take(sizeof(int) * E);
    float*  invnA   = (float*) take(sizeof(float) * N);
    float*  invnB   = (float*) take(sizeof(float) * N);
    __half* xh      = (__half*)take(sizeof(__half) * N * D_FEAT_C);
    __half* h1h     = (__half*)take(sizeof(__half) * N * D_FEAT_C);

    // CSR by dst (layer-invariant)
    hipMemsetAsync(deg, 0, sizeof(int) * N, stream);
    deg_kernel<<<(E + 255) / 256, 256, 0, stream>>>(dst, deg, E);
    exscan_kernel<<<1, 1024, 0, stream>>>(deg, offs, cursor, N);
    fill_kernel<<<(E + 255) / 256, 256, 0, stream>>>(src, dst, cursor, csr_src, E);

    const int node_blocks = (N + 3) / 4;   // 4 waves (nodes) per 256-thread block

    // layer 0: x -> h1h (half) + invnB
    invnorm_cvt_kernel<<<node_blocks, 256, 0, stream>>>(x, invnA, xh, N);
    agnn_node_kernel<<<node_blocks, 256, 0, stream>>>(xh, invnA, offs, csr_src, beta, 0,
                                                      nullptr, h1h, invnB, N);

    // layer 1: h1h -> out (fp32)
    agnn_node_kernel<<<node_blocks, 256, 0, stream>>>(h1h, invnB, offs, csr_src, beta, 1,
                                                      out, nullptr, nullptr, N);
}

// Round 8
// 188.685 us; speedup vs baseline: 1.4941x; 1.0131x over previous
//
#include <hip/hip_runtime.h>
#include <hip/hip_fp16.h>
#include <math.h>

#define N_NODES_C 50000
#define N_EDGES_C 800000
#define D_FEAT_C  64
#define NPART 8                      // one partition per XCD
#define PART_SZ (N_NODES_C / NPART)  // 6250 (divides exactly)

// ---------------- CSR build (XCD-partitioned scatter) ----------------

// Block b: part = b & 7 (maps to XCD via round-robin dispatch), chunk = b >> 3.
// Each part's blocks collectively scan all edges but only touch deg entries in
// their dst range -> per-XCD-private cache lines, no cross-XCD writebacks.
__global__ void deg_part_kernel(const int* __restrict__ dst, int* __restrict__ deg, int nE) {
    const int part = blockIdx.x & (NPART - 1);
    const int chunk = blockIdx.x >> 3;
    const int nchunk = gridDim.x >> 3;
    const int lo = part * PART_SZ, hi = lo + PART_SZ;
    for (int i = chunk * blockDim.x + threadIdx.x; i < nE; i += nchunk * blockDim.x) {
        int d = dst[i];
        if (d >= lo && d < hi) atomicAdd(&deg[d], 1);
    }
}

// Single-block exclusive scan, 4 elements/thread (int4). n must be mult of 4 (50000 is).
__global__ void exscan_kernel(const int* __restrict__ deg, int* __restrict__ offs,
                              int* __restrict__ cursor, int n) {
    __shared__ int lds[16];
    __shared__ int carry_s;
    const int tid  = threadIdx.x;          // blockDim.x == 1024
    const int lane = tid & 63;
    const int wid  = tid >> 6;             // 16 waves
    if (tid == 0) carry_s = 0;
    __syncthreads();
    for (int base = 0; base < n; base += 4096) {
        int i = base + tid * 4;
        int4 v = make_int4(0, 0, 0, 0);
        if (i < n) v = *(const int4*)(deg + i);   // n%4==0 -> safe
        int tsum = v.x + v.y + v.z + v.w;
        int x = tsum;
        #pragma unroll
        for (int off = 1; off < 64; off <<= 1) {
            int y = __shfl_up(x, off, 64);
            if (lane >= off) x += y;
        }
        if (lane == 63) lds[wid] = x;
        __syncthreads();
        if (tid < 16) {
            int w = lds[tid];
            #pragma unroll
            for (int off = 1; off < 16; off <<= 1) {
                int y = __shfl_up(w, off, 16);
                if (tid >= off) w += y;
            }
            lds[tid] = w;
        }
        __syncthreads();
        int waveoff = wid ? lds[wid - 1] : 0;
        int excl = carry_s + waveoff + (x - tsum);
        if (i < n) {
            int4 o;
            o.x = excl;
            o.y = o.x + v.x;
            o.z = o.y + v.y;
            o.w = o.z + v.z;
            *(int4*)(offs + i)   = o;
            *(int4*)(cursor + i) = o;
        }
        __syncthreads();
        if (tid == 1023) carry_s += lds[15];
        __syncthreads();
    }
    if (tid == 0) offs[n] = carry_s;
}

// XCD-partitioned fill: XCD k writes only csr_src[offs[lo_k]..offs[hi_k]) and
// cursor[lo_k..hi_k) -> write lines stay private to one XCD's L2.
__global__ void fill_part_kernel(const int* __restrict__ src, const int* __restrict__ dst,
                                 int* __restrict__ cursor, int* __restrict__ csr_src, int nE) {
    const int part = blockIdx.x & (NPART - 1);
    const int chunk = blockIdx.x >> 3;
    const int nchunk = gridDim.x >> 3;
    const int lo = part * PART_SZ, hi = lo + PART_SZ;
    for (int i = chunk * blockDim.x + threadIdx.x; i < nE; i += nchunk * blockDim.x) {
        int d = dst[i];
        if (d >= lo && d < hi) {
            int pos = atomicAdd(&cursor[d], 1);
            csr_src[pos] = src[i];
        }
    }
}

// ---------------- per-layer kernels ----------------

// Wave per node: 1/max(||row||,eps) from fp32 x, plus fused fp32->fp16 row copy.
__global__ void invnorm_cvt_kernel(const float* __restrict__ h, float* __restrict__ invn,
                                   __half* __restrict__ hh, int n) {
    int wave = (blockIdx.x * blockDim.x + threadIdx.x) >> 6;
    int lane = threadIdx.x & 63;
    if (wave >= n) return;
    float x = h[wave * D_FEAT_C + lane];
    hh[wave * D_FEAT_C + lane] = __float2half(x);
    float ss = x * x;
    #pragma unroll
    for (int off = 32; off; off >>= 1) ss += __shfl_xor(ss, off, 64);
    if (lane == 0) invn[wave] = 1.0f / fmaxf(sqrtf(ss), 1e-12f);
}

// Wave per dst node; quarter-wave (16 lanes x 4 features) per edge, 4 edges/chunk.
// (unchanged from R6 -- proven structure)
__global__ void __launch_bounds__(256)
agnn_node_kernel(const __half* __restrict__ hh, const float* __restrict__ invn,
                 const int* __restrict__ offs, const int* __restrict__ csr_src,
                 const float* __restrict__ beta_ptr, int layer,
                 float* __restrict__ outF, __half* __restrict__ outH,
                 float* __restrict__ invn_out, int n) {
    int wave = (blockIdx.x * blockDim.x + threadIdx.x) >> 6;
    int lane = threadIdx.x & 63;
    if (wave >= n) return;
    int s = offs[wave], e = offs[wave + 1];
    const int q16 = lane >> 4;   // quarter (edge slot in chunk)
    const int fl  = lane & 15;   // feature group: features 4*fl .. 4*fl+3
    float4 ro = make_float4(0.f, 0.f, 0.f, 0.f);
    if (e > s) {                              // wave-uniform
        float invd = invn[wave];
        float bi   = beta_ptr[layer] * invd;
        uint2 ndl = *(const uint2*)(hh + wave * D_FEAT_C + 4 * fl);
        float2 n0 = __half22float2(*(__half2*)&ndl.x);
        float2 n1 = __half22float2(*(__half2*)&ndl.y);
        float m = -INFINITY, den = 0.f;
        float4 acc = make_float4(0.f, 0.f, 0.f, 0.f);
        for (int base = s; base < e; base += 64) {
            int idx  = base + lane;
            int eidx = (idx < e) ? csr_src[idx] : 0;   // coalesced batch of 64 edge ids
            int nb   = min(64, e - base);               // wave-uniform
            for (int jj = 0; jj < nb; jj += 4) {
                int  t     = jj + q16;
                bool valid = t < nb;                    // uniform within quarter
                int  tc    = valid ? t : jj;
                int  u     = __shfl(eidx, tc, 64);      // per-quarter src id
                float iu   = invn[u];
                uint2 hul  = *(const uint2*)(hh + u * D_FEAT_C + 4 * fl);  // 8B -> 512B/wave
                float2 f0  = __half22float2(*(__half2*)&hul.x);
                float2 f1  = __half22float2(*(__half2*)&hul.y);
                float d = f0.x * n0.x + f0.y * n0.y + f1.x * n1.x + f1.y * n1.y;
                d += __shfl_xor(d, 1, 64);
                d += __shfl_xor(d, 2, 64);
                d += __shfl_xor(d, 4, 64);
                d += __shfl_xor(d, 8, 64);              // full dot, uniform in quarter
                float sc = valid ? bi * d * iu : -INFINITY;
                float M4 = fmaxf(sc, __shfl_xor(sc, 16, 64));
                M4 = fmaxf(M4, __shfl_xor(M4, 32, 64)); // chunk max, wave-uniform
                float M  = fmaxf(m, M4);
                float w  = __expf(sc - M);              // 0 for invalid slots
                float scale = __expf(m - M);            // 0 on first chunk
                den   = den   * scale + w;              // own-quarter partial
                acc.x = acc.x * scale + w * f0.x;
                acc.y = acc.y * scale + w * f0.y;
                acc.z = acc.z * scale + w * f1.x;
                acc.w = acc.w * scale + w * f1.y;
                m = M;
            }
        }
        // cross-quarter reduction (same m everywhere -> exact)
        den += __shfl_xor(den, 16, 64);  den += __shfl_xor(den, 32, 64);
        acc.x += __shfl_xor(acc.x, 16, 64);  acc.x += __shfl_xor(acc.x, 32, 64);
        acc.y += __shfl_xor(acc.y, 16, 64);  acc.y += __shfl_xor(acc.y, 32, 64);
        acc.z += __shfl_xor(acc.z, 16, 64);  acc.z += __shfl_xor(acc.z, 32, 64);
        acc.w += __shfl_xor(acc.w, 16, 64);  acc.w += __shfl_xor(acc.w, 32, 64);
        float inv_den = 1.0f / den;
        ro.x = fmaxf(acc.x * inv_den, 0.f);
        ro.y = fmaxf(acc.y * inv_den, 0.f);
        ro.z = fmaxf(acc.z * inv_den, 0.f);
        ro.w = fmaxf(acc.w * inv_den, 0.f);
    }
    // all quarters hold identical ro (features 4*fl..+3); quarter 0 writes
    if (outF && lane < 16) ((float4*)(outF + wave * D_FEAT_C))[fl] = ro;
    if (outH && lane < 16) {
        __half2 a = __floats2half2_rn(ro.x, ro.y);
        __half2 b = __floats2half2_rn(ro.z, ro.w);
        uint2 pk;
        pk.x = *(unsigned*)&a;
        pk.y = *(unsigned*)&b;
        *(uint2*)(outH + wave * D_FEAT_C + 4 * fl) = pk;
    }
    if (invn_out) {
        float ss = ro.x * ro.x + ro.y * ro.y + ro.z * ro.z + ro.w * ro.w;
        ss += __shfl_xor(ss, 1, 64);
        ss += __shfl_xor(ss, 2, 64);
        ss += __shfl_xor(ss, 4, 64);
        ss += __shfl_xor(ss, 8, 64);        // sum within quarter = full ||row||^2
        if (lane == 0) invn_out[wave] = 1.0f / fmaxf(sqrtf(ss), 1e-12f);
    }
}

// ---------------- launch ----------------

extern "C" void kernel_launch(void* const* d_in, const int* in_sizes, int n_in,
                              void* d_out, int out_size, void* d_ws, size_t ws_size,
                              hipStream_t stream) {
    const float* x    = (const float*)d_in[0];
    const int*   src  = (const int*)d_in[1];
    const int*   dst  = (const int*)d_in[2];
    const float* beta = (const float*)d_in[3];
    float*       out  = (float*)d_out;

    const int N = N_NODES_C, E = N_EDGES_C;

    char* p = (char*)d_ws;
    auto take = [&](size_t bytes) { char* r = p; p += (bytes + 255) & ~size_t(255); return r; };
    int*    deg     = (int*)   take(sizeof(int) * N);
    int*    offs    = (int*)   take(sizeof(int) * (N + 1));
    int*    cursor  = (int*)   take(sizeof(int) * N);
    int*    csr_src = (int*)   take(sizeof(int) * E);
    float*  invnA   = (float*) take(sizeof(float) * N);
    float*  invnB   = (float*) take(sizeof(float) * N);
    __half* xh      = (__half*)take(sizeof(__half) * N * D_FEAT_C);
    __half* h1h     = (__half*)take(sizeof(__half) * N * D_FEAT_C);

    // CSR by dst (layer-invariant), XCD-partitioned scatter
    hipMemsetAsync(deg, 0, sizeof(int) * N, stream);
    deg_part_kernel<<<512, 256, 0, stream>>>(dst, deg, E);       // 64 chunks x 8 parts
    exscan_kernel<<<1, 1024, 0, stream>>>(deg, offs, cursor, N);
    fill_part_kernel<<<512, 256, 0, stream>>>(src, dst, cursor, csr_src, E);

    const int node_blocks = (N + 3) / 4;   // 4 waves (nodes) per 256-thread block

    // layer 0: x -> h1h (half) + invnB
    invnorm_cvt_kernel<<<node_blocks, 256, 0, stream>>>(x, invnA, xh, N);
    agnn_node_kernel<<<node_blocks, 256, 0, stream>>>(xh, invnA, offs, csr_src, beta, 0,
                                                      nullptr, h1h, invnB, N);

    // layer 1: h1h -> out (fp32)
    agnn_node_kernel<<<node_blocks, 256, 0, stream>>>(h1h, invnB, offs, csr_src, beta, 1,
                                                      out, nullptr, nullptr, N);
}